// Round 1
// baseline (1863.595 us; speedup 1.0000x reference)
//
#include <hip/hip_runtime.h>
#include <math.h>

#define B 8
#define C 128
#define H 160
#define W 160
#define HW 25600

// ---------------- weight repack ----------------
// wT[ci][k][co] layouts so the conv inner loop over cout reads contiguous,
// block-uniform floats (compiler emits s_load_dwordxN broadcasts).
__global__ void k_repack(const float* __restrict__ w1, const float* __restrict__ w2,
                         const float* __restrict__ w3, const float* __restrict__ dw,
                         const float* __restrict__ cw,
                         float* __restrict__ wT1, float* __restrict__ wT2,
                         float* __restrict__ wT3, float* __restrict__ wHT) {
    int i = blockIdx.x * 256 + threadIdx.x;
    if (i < 57600) {  // w1: Cin=50, Cout=128, 9 taps
        int ci = i / 1152; int rem = i % 1152; int k = rem / 128; int co = rem % 128;
        wT1[i] = w1[(co * 50 + ci) * 9 + k];
        return;
    }
    i -= 57600;
    if (i < 73728) {  // w2: Cin=128, Cout=64
        int ci = i / 576; int rem = i % 576; int k = rem / 64; int co = rem % 64;
        wT2[i] = w2[(co * 128 + ci) * 9 + k];
        return;
    }
    i -= 73728;
    if (i < 18432) {  // w3: Cin=64, Cout=32
        int ci = i / 288; int rem = i % 288; int k = rem / 32; int co = rem % 32;
        wT3[i] = w3[(co * 64 + ci) * 9 + k];
        return;
    }
    i -= 18432;
    if (i < 2400) {   // heads: Cin=32, 25 taps, co: 0,1=disp  2=conf
        int ci = i / 75; int rem = i % 75; int k = rem / 3; int co = rem % 3;
        wHT[i] = (co < 2) ? dw[(co * 32 + ci) * 25 + k] : cw[ci * 25 + k];
    }
}

// ---------------- deconv upsample (stride 2, pad 1, k=4) ----------------
// out[y,x] = sum_{dy,dx} in[(y+1-dy)/2, (x+1-dx)/2] * w[dy,dx]  (even taps only)
__global__ void k_upsample(const float* __restrict__ flow, const float* __restrict__ conf,
                           const float* __restrict__ up_flow_w, const float* __restrict__ up_conf_w,
                           float* __restrict__ flow_up, float* __restrict__ xin) {
    int idx = blockIdx.x * 256 + threadIdx.x;
    if (idx >= B * 3 * HW) return;
    int x = idx % W;
    int y = (idx / W) % H;
    int ch = (idx / HW) % 3;
    int b = idx / (3 * HW);
    const float* in;
    const float* w;
    if (ch < 2) { in = flow + (size_t)(b * 2 + ch) * 6400; w = up_flow_w + ch * 16; }
    else        { in = conf + (size_t)b * 6400;            w = up_conf_w; }
    float acc = 0.f;
#pragma unroll
    for (int dy = 0; dy < 4; ++dy) {
        int tny = y + 1 - dy;
        if (tny < 0 || (tny & 1)) continue;
        int iy = tny >> 1;
        if (iy >= 80) continue;
#pragma unroll
        for (int dx = 0; dx < 4; ++dx) {
            int tnx = x + 1 - dx;
            if (tnx < 0 || (tnx & 1)) continue;
            int ix = tnx >> 1;
            if (ix >= 80) continue;
            acc += in[iy * 80 + ix] * w[dy * 4 + dx];
        }
    }
    if (ch < 2) flow_up[(size_t)(b * 2 + ch) * HW + y * W + x] = acc;
    else        xin[((size_t)b * 50 + 49) * HW + y * W + x] = acc;  // conf is channel 49
}

// ---------------- dilated self-correlation (PATCH=7, DIL=2) ----------------
// block (32,8): 32x8 pixel tile; LDS tile 20x44 per channel (halo 6).
// wave = 2 rows of 32 lanes; row stride 44 ≡ 12 (mod 32) → 2-way bank aliasing (free).
__global__ __launch_bounds__(256) void k_corr(const float* __restrict__ feats,
                                              float* __restrict__ xin) {
    const int b = blockIdx.z;
    const int x0 = blockIdx.x * 32;
    const int y0 = blockIdx.y * 8;
    const int tx = threadIdx.x, ty = threadIdx.y;
    const int tid = ty * 32 + tx;
    __shared__ float sh[20 * 44];
    float acc[49];
#pragma unroll
    for (int i = 0; i < 49; ++i) acc[i] = 0.f;
    const float* f = feats + (size_t)b * 2 * C * HW;  // feats[b, 0]
    for (int c = 0; c < C; ++c) {
        const float* fc = f + (size_t)c * HW;
        __syncthreads();
        for (int i = tid; i < 880; i += 256) {
            int r = i / 44, cc = i % 44;
            int gy = y0 + r - 6, gx = x0 + cc - 6;
            float v = 0.f;
            if (gy >= 0 && gy < H && gx >= 0 && gx < W) v = fc[gy * W + gx];
            sh[i] = v;
        }
        __syncthreads();
        float ctr = sh[(ty + 6) * 44 + tx + 6];
#pragma unroll
        for (int dy = 0; dy < 7; ++dy)
#pragma unroll
            for (int dx = 0; dx < 7; ++dx)
                acc[dy * 7 + dx] += ctr * sh[(ty + 2 * dy) * 44 + (tx + 2 * dx)];
    }
    float* outp = xin + (size_t)b * 50 * HW + (y0 + ty) * W + (x0 + tx);
#pragma unroll
    for (int k = 0; k < 49; ++k) {
        float v = acc[k];
        v = (v > 0.f) ? v : 0.1f * v;           // leaky_relu(0.1)
        outp[(size_t)k * HW] = v * 0.0078125f;  // / 128
    }
}

// ---------------- generic 3x3 conv + bias + leaky_relu ----------------
// block (16,16): 16x16 pixel tile, 16 output channels per block (grid.y).
// Weights wT[ci][k][co] read with block-uniform index → scalar broadcast loads.
__global__ __launch_bounds__(256) void k_conv3(const float* __restrict__ in,
                                               const float* __restrict__ wT,
                                               const float* __restrict__ bias,
                                               float* __restrict__ out,
                                               int Cin, int Cout) {
    const int b = blockIdx.z;
    const int x0 = (blockIdx.x % 10) * 16;
    const int y0 = (blockIdx.x / 10) * 16;
    const int cob = blockIdx.y * 16;
    const int tx = threadIdx.x, ty = threadIdx.y;
    const int tid = ty * 16 + tx;
    __shared__ float sh[2 * 324];  // 2 channels x 18x18
    float acc[16];
#pragma unroll
    for (int r = 0; r < 16; ++r) acc[r] = bias[cob + r];
    const float* inb = in + (size_t)(b * Cin) * HW;
    for (int ci = 0; ci < Cin; ci += 2) {
        __syncthreads();
        for (int i = tid; i < 648; i += 256) {
            int cc = i / 324;
            int rem = i - cc * 324;
            int r = rem / 18, c2 = rem % 18;
            int gy = y0 + r - 1, gx = x0 + c2 - 1;
            float v = 0.f;
            if (gy >= 0 && gy < H && gx >= 0 && gx < W)
                v = inb[(size_t)(ci + cc) * HW + gy * W + gx];
            sh[i] = v;
        }
        __syncthreads();
#pragma unroll
        for (int cc = 0; cc < 2; ++cc) {
            const float* t = sh + cc * 324;
            const float* wp = wT + ((size_t)(ci + cc) * 9) * Cout + cob;
#pragma unroll
            for (int k = 0; k < 9; ++k) {
                float v = t[(ty + k / 3) * 18 + tx + (k % 3)];
                const float* wk = wp + k * Cout;
#pragma unroll
                for (int r = 0; r < 16; ++r)
                    acc[r] += v * wk[r];
            }
        }
    }
    float* op = out + ((size_t)(b * Cout + cob)) * HW + (y0 + ty) * W + (x0 + tx);
#pragma unroll
    for (int r = 0; r < 16; ++r) {
        float v = acc[r];
        v = (v > 0.f) ? v : 0.1f * v;
        op[(size_t)r * HW] = v;
    }
}

// ---------------- fused heads (5x5 convs) + warp + sigmoid ----------------
__global__ __launch_bounds__(256) void k_head(const float* __restrict__ x3,
                                              const float* __restrict__ wHT,
                                              const float* __restrict__ disp_b,
                                              const float* __restrict__ conf_b,
                                              const float* __restrict__ flow_up,
                                              float* __restrict__ out) {
    const int b = blockIdx.z;
    const int x0 = blockIdx.x * 16, y0 = blockIdx.y * 16;
    const int tx = threadIdx.x, ty = threadIdx.y;
    const int tid = ty * 16 + tx;
    __shared__ float sh[2 * 400];  // 2 channels x 20x20
    float a0 = 0.f, a1 = 0.f, a2 = 0.f;
    const float* xb = x3 + (size_t)(b * 32) * HW;
    for (int ci = 0; ci < 32; ci += 2) {
        __syncthreads();
        for (int i = tid; i < 800; i += 256) {
            int cc = i / 400;
            int rem = i - cc * 400;
            int r = rem / 20, c2 = rem % 20;
            int gy = y0 + r - 2, gx = x0 + c2 - 2;
            float v = 0.f;
            if (gy >= 0 && gy < H && gx >= 0 && gx < W)
                v = xb[(size_t)(ci + cc) * HW + gy * W + gx];
            sh[i] = v;
        }
        __syncthreads();
#pragma unroll
        for (int cc = 0; cc < 2; ++cc) {
            const float* t = sh + cc * 400;
            const float* wp = wHT + (size_t)(ci + cc) * 75;
#pragma unroll
            for (int k = 0; k < 25; ++k) {
                float v = t[(ty + k / 5) * 20 + tx + (k % 5)];
                a0 += v * wp[k * 3 + 0];
                a1 += v * wp[k * 3 + 1];
                a2 += v * wp[k * 3 + 2];
            }
        }
    }
    const int gx = x0 + tx, gy = y0 + ty;
    float d0 = a0 + disp_b[0];
    float d1 = a1 + disp_b[1];
    float cf = a2 + conf_b[0];
    cf = 1.f / (1.f + expf(-cf));

    // bilinear warp of flow_up at (gx + d0, gy + d1), border-masked
    float px = (float)gx + d0, py = (float)gy + d1;
    float x0f = floorf(px), y0f = floorf(py);
    float wx1 = px - x0f, wx0 = 1.f - wx1;
    float wy1 = py - y0f, wy0 = 1.f - wy1;
    const float* f0 = flow_up + (size_t)(b * 2) * HW;
    const float* f1 = f0 + HW;

    float m00, m01, m10, m11;
    float a00, a01, a10, a11;
    float b00, b01, b10, b11;
    auto corner = [&](float xf, float yf, float& m, float& c0, float& c1) {
        bool valid = (xf >= 0.f) && (xf <= (float)(W - 1)) && (yf >= 0.f) && (yf <= (float)(H - 1));
        m = valid ? 1.f : 0.f;
        if (valid) {
            int xi = (int)xf, yi = (int)yf;
            int o = yi * W + xi;
            c0 = f0[o]; c1 = f1[o];
        } else { c0 = 0.f; c1 = 0.f; }
    };
    corner(x0f,       y0f,       m00, a00, b00);
    corner(x0f + 1.f, y0f,       m01, a01, b01);
    corner(x0f,       y0f + 1.f, m10, a10, b10);
    corner(x0f + 1.f, y0f + 1.f, m11, a11, b11);

    float o0 = wy0 * (wx0 * a00 + wx1 * a01) + wy1 * (wx0 * a10 + wx1 * a11);
    float o1 = wy0 * (wx0 * b00 + wx1 * b01) + wy1 * (wx0 * b10 + wx1 * b11);
    float msk = wy0 * (wx0 * m00 + wx1 * m01) + wy1 * (wx0 * m10 + wx1 * m11);
    float mask = (msk >= 1.f) ? 1.f : 0.f;

    int o = gy * W + gx;
    out[(size_t)(b * 2 + 0) * HW + o] = o0 * mask;
    out[(size_t)(b * 2 + 1) * HW + o] = o1 * mask;
    out[(size_t)B * 2 * HW + (size_t)b * HW + o] = cf;
}

extern "C" void kernel_launch(void* const* d_in, const int* in_sizes, int n_in,
                              void* d_out, int out_size, void* d_ws, size_t ws_size,
                              hipStream_t stream) {
    const float* feats     = (const float*)d_in[0];
    const float* flow      = (const float*)d_in[1];
    const float* conf      = (const float*)d_in[2];
    const float* up_conf_w = (const float*)d_in[3];
    const float* up_flow_w = (const float*)d_in[4];
    const float* w1        = (const float*)d_in[5];
    const float* b1        = (const float*)d_in[6];
    const float* w2        = (const float*)d_in[7];
    const float* b2        = (const float*)d_in[8];
    const float* w3        = (const float*)d_in[9];
    const float* b3        = (const float*)d_in[10];
    const float* disp_w    = (const float*)d_in[11];
    const float* disp_b    = (const float*)d_in[12];
    const float* conf_w    = (const float*)d_in[13];
    const float* conf_b    = (const float*)d_in[14];
    float* out = (float*)d_out;

    float* ws = (float*)d_ws;
    // workspace layout (floats)
    float* xin     = ws;                      // B*50*HW  = 10,240,000  (corr 0..48, conf ch49)
    float* x1      = xin + (size_t)10240000;  // B*128*HW = 26,214,400
    float* x2      = x1  + (size_t)26214400;  // B*64*HW  = 13,107,200
    float* flow_up = x2  + (size_t)13107200;  // B*2*HW   =    409,600
    float* wT1     = flow_up + (size_t)409600;   // 57,600
    float* wT2     = wT1 + (size_t)57600;        // 73,728
    float* wT3     = wT2 + (size_t)73728;        // 18,432
    float* wHT     = wT3 + (size_t)18432;        //  2,400
    float* x3      = xin;  // alias: xin is dead after conv1

    k_repack<<<(152160 + 255) / 256, 256, 0, stream>>>(w1, w2, w3, disp_w, conf_w,
                                                       wT1, wT2, wT3, wHT);
    k_upsample<<<(B * 3 * HW + 255) / 256, 256, 0, stream>>>(flow, conf, up_flow_w, up_conf_w,
                                                             flow_up, xin);
    k_corr<<<dim3(5, 20, B), dim3(32, 8), 0, stream>>>(feats, xin);
    k_conv3<<<dim3(100, 8, B), dim3(16, 16), 0, stream>>>(xin, wT1, b1, x1, 50, 128);
    k_conv3<<<dim3(100, 4, B), dim3(16, 16), 0, stream>>>(x1, wT2, b2, x2, 128, 64);
    k_conv3<<<dim3(100, 2, B), dim3(16, 16), 0, stream>>>(x2, wT3, b3, x3, 64, 32);
    k_head<<<dim3(10, 10, B), dim3(16, 16), 0, stream>>>(x3, wHT, disp_b, conf_b, flow_up, out);
}

// Round 2
// 1176.655 us; speedup vs baseline: 1.5838x; 1.5838x over previous
//
#include <hip/hip_runtime.h>
#include <math.h>

#define B 8
#define C 128
#define H 160
#define W 160
#define HW 25600
#define WP 162   // padded width/height (pad=1 ring of zeros)

typedef short bf16x8 __attribute__((ext_vector_type(8)));
typedef float f32x4  __attribute__((ext_vector_type(4)));

__device__ __forceinline__ unsigned short f2bf(float x) {  // RNE
    union { float f; unsigned u; } v; v.f = x;
    unsigned r = v.u + 0x7fff + ((v.u >> 16) & 1);
    return (unsigned short)(r >> 16);
}
__device__ __forceinline__ float bf2f(unsigned short h) {
    union { unsigned u; float f; } v; v.u = ((unsigned)h) << 16;
    return v.f;
}

// ---------------- weight repack: split-bf16 [tap][co][ci] ----------------
__global__ void k_repack(const float* __restrict__ w1, const float* __restrict__ w2,
                         const float* __restrict__ w3, const float* __restrict__ dw,
                         const float* __restrict__ cw,
                         unsigned short* __restrict__ wpk1h, unsigned short* __restrict__ wpk1l,
                         unsigned short* __restrict__ wpk2h, unsigned short* __restrict__ wpk2l,
                         unsigned short* __restrict__ wpk3h, unsigned short* __restrict__ wpk3l,
                         float* __restrict__ wHT) {
    int idx = blockIdx.x * 256 + threadIdx.x;
    if (idx < 73728) {  // w1: [t][co=128][ci=64]  (ci 0..49 real, 50..63 zero)
        int t = idx / 8192; int r = idx % 8192; int co = r / 64; int ci = r % 64;
        float v = (ci < 50) ? w1[(co * 50 + ci) * 9 + t] : 0.f;
        unsigned short h = f2bf(v);
        wpk1h[idx] = h; wpk1l[idx] = f2bf(v - bf2f(h));
        return;
    }
    idx -= 73728;
    if (idx < 73728) {  // w2: [t][co=64][ci=128]
        int t = idx / 8192; int r = idx % 8192; int co = r / 128; int ci = r % 128;
        float v = w2[(co * 128 + ci) * 9 + t];
        unsigned short h = f2bf(v);
        wpk2h[idx] = h; wpk2l[idx] = f2bf(v - bf2f(h));
        return;
    }
    idx -= 73728;
    if (idx < 18432) {  // w3: [t][co=32][ci=64]
        int t = idx / 2048; int r = idx % 2048; int co = r / 64; int ci = r % 64;
        float v = w3[(co * 64 + ci) * 9 + t];
        unsigned short h = f2bf(v);
        wpk3h[idx] = h; wpk3l[idx] = f2bf(v - bf2f(h));
        return;
    }
    idx -= 18432;
    if (idx < 2400) {   // heads (fp32): wHT[ci][k][3]: 0,1=disp 2=conf
        int ci = idx / 75; int rem = idx % 75; int k = rem / 3; int co = rem % 3;
        wHT[idx] = (co < 2) ? dw[(co * 32 + ci) * 25 + k] : cw[ci * 25 + k];
    }
}

// ---------------- zero the pad rings of xin (C=64) and x1 (C=128) ----------------
__global__ void k_zeropad(unsigned short* __restrict__ xin_hi, unsigned short* __restrict__ xin_lo,
                          unsigned short* __restrict__ x1_hi,  unsigned short* __restrict__ x1_lo) {
    int idx = blockIdx.x * 256 + threadIdx.x;
    unsigned short *ph, *pl; int Cc;
    if (idx < 41216) { ph = xin_hi; pl = xin_lo; Cc = 64; }
    else {
        idx -= 41216;
        if (idx >= 82432) return;
        ph = x1_hi; pl = x1_lo; Cc = 128;
    }
    int chunks = Cc / 8;
    int img = idx / (644 * chunks);
    int r = idx % (644 * chunks);
    int rp = r / chunks; int ch = r % chunks;
    int yy, xx;
    if (rp < 162)      { yy = 0;   xx = rp; }
    else if (rp < 324) { yy = 161; xx = rp - 162; }
    else { int s = rp - 324; yy = 1 + (s >> 1); xx = (s & 1) ? 161 : 0; }
    size_t off = ((size_t)(img * WP + yy) * WP + xx) * Cc + ch * 8;
    bf16x8 z = {0, 0, 0, 0, 0, 0, 0, 0};
    *(bf16x8*)&ph[off] = z;
    *(bf16x8*)&pl[off] = z;
}

// ---------------- deconv upsample (stride 2, pad 1, k=4) ----------------
__global__ void k_upsample(const float* __restrict__ flow, const float* __restrict__ conf,
                           const float* __restrict__ up_flow_w, const float* __restrict__ up_conf_w,
                           float* __restrict__ flow_up,
                           unsigned short* __restrict__ xin_hi, unsigned short* __restrict__ xin_lo) {
    int idx = blockIdx.x * 256 + threadIdx.x;
    if (idx >= B * 3 * HW) return;
    int x = idx % W;
    int y = (idx / W) % H;
    int ch = (idx / HW) % 3;
    int b = idx / (3 * HW);
    const float* in;
    const float* w;
    if (ch < 2) { in = flow + (size_t)(b * 2 + ch) * 6400; w = up_flow_w + ch * 16; }
    else        { in = conf + (size_t)b * 6400;            w = up_conf_w; }
    float acc = 0.f;
#pragma unroll
    for (int dy = 0; dy < 4; ++dy) {
        int tny = y + 1 - dy;
        if (tny < 0 || (tny & 1)) continue;
        int iy = tny >> 1;
        if (iy >= 80) continue;
#pragma unroll
        for (int dx = 0; dx < 4; ++dx) {
            int tnx = x + 1 - dx;
            if (tnx < 0 || (tnx & 1)) continue;
            int ix = tnx >> 1;
            if (ix >= 80) continue;
            acc += in[iy * 80 + ix] * w[dy * 4 + dx];
        }
    }
    if (ch < 2) flow_up[(size_t)(b * 2 + ch) * HW + y * W + x] = acc;
    else {
        // conf is channel 49 of the padded NHWC(64) conv1 input
        size_t off = ((size_t)(b * WP + y + 1) * WP + (x + 1)) * 64 + 49;
        unsigned short h = f2bf(acc);
        xin_hi[off] = h;
        xin_lo[off] = f2bf(acc - bf2f(h));
    }
}

// ---------------- dilated self-correlation (PATCH=7, DIL=2) ----------------
// writes NHWC(64) padded split-bf16: ch 0..48 = corr, ch 50..63 = 0 (49=conf by upsample)
__global__ __launch_bounds__(256) void k_corr(const float* __restrict__ feats,
                                              unsigned short* __restrict__ xin_hi,
                                              unsigned short* __restrict__ xin_lo) {
    const int b = blockIdx.z;
    const int x0 = blockIdx.x * 32;
    const int y0 = blockIdx.y * 8;
    const int tx = threadIdx.x, ty = threadIdx.y;
    const int tid = ty * 32 + tx;
    __shared__ float sh[20 * 44];
    float acc[49];
#pragma unroll
    for (int i = 0; i < 49; ++i) acc[i] = 0.f;
    const float* f = feats + (size_t)b * 2 * C * HW;  // feats[b, 0]
    for (int c = 0; c < C; ++c) {
        const float* fc = f + (size_t)c * HW;
        __syncthreads();
        for (int i = tid; i < 880; i += 256) {
            int r = i / 44, cc = i % 44;
            int gy = y0 + r - 6, gx = x0 + cc - 6;
            float v = 0.f;
            if (gy >= 0 && gy < H && gx >= 0 && gx < W) v = fc[gy * W + gx];
            sh[i] = v;
        }
        __syncthreads();
        float ctr = sh[(ty + 6) * 44 + tx + 6];
#pragma unroll
        for (int dy = 0; dy < 7; ++dy)
#pragma unroll
            for (int dx = 0; dx < 7; ++dx)
                acc[dy * 7 + dx] += ctr * sh[(ty + 2 * dy) * 44 + (tx + 2 * dx)];
    }
    size_t pbase = ((size_t)(b * WP + y0 + ty + 1) * WP + (x0 + tx + 1)) * 64;
#pragma unroll
    for (int k = 0; k < 49; ++k) {
        float v = acc[k];
        v = (v > 0.f) ? v : 0.1f * v;           // leaky_relu(0.1)
        v *= 0.0078125f;                        // / 128
        unsigned short h = f2bf(v);
        xin_hi[pbase + k] = h;
        xin_lo[pbase + k] = f2bf(v - bf2f(h));
    }
#pragma unroll
    for (int k = 50; k < 64; ++k) { xin_hi[pbase + k] = 0; xin_lo[pbase + k] = 0; }
}

// ---------------- split-bf16 MFMA 3x3 conv + bias + leaky_relu ----------------
// Implicit GEMM per tap: M=pixels, N=cout, K=cin. Wave = 80 px (5 m-tiles) x COUT.
// A (activations) from padded NHWC global (L1-hot across 9 taps); B (weights) from
// LDS, staged per tap, pitch CIN+8 halves to break bank alignment.
// 3 MFMAs per fp32 MAC: hi*hi + hi*lo + lo*hi (error ~2^-17 rel, fp32-class).
template<int CIN, int COUT, int OUTF>
__global__ __launch_bounds__(256, 1) void k_convM(
    const unsigned short* __restrict__ in_hi, const unsigned short* __restrict__ in_lo,
    const unsigned short* __restrict__ w_hi,  const unsigned short* __restrict__ w_lo,
    const float* __restrict__ bias,
    unsigned short* __restrict__ out_hi, unsigned short* __restrict__ out_lo,
    float* __restrict__ out_f) {
    constexpr int NT = COUT / 16;
    constexpr int PITCH = CIN + 8;
    constexpr int CH = CIN / 8;
    __shared__ unsigned short wl[2 * COUT * PITCH];
    const int b = blockIdx.z;
    const int wave = threadIdx.x >> 6;
    const int lane = threadIdx.x & 63;
    const int y = blockIdx.x * 2 + (wave >> 1);   // interior row 0..159
    const int x0 = (wave & 1) * 80;
    const int m = lane & 15, q = lane >> 4;
    f32x4 acc[5][NT];
#pragma unroll
    for (int mt = 0; mt < 5; ++mt)
#pragma unroll
        for (int nt = 0; nt < NT; ++nt) acc[mt][nt] = (f32x4){0.f, 0.f, 0.f, 0.f};
    int abase[5];
#pragma unroll
    for (int mt = 0; mt < 5; ++mt)
        abase[mt] = ((b * WP + y) * WP + x0 + mt * 16 + m) * CIN + q * 8;

    for (int tap = 0; tap < 9; ++tap) {
        const int tapoff = ((tap / 3) * WP + (tap % 3)) * CIN;
        __syncthreads();
        for (int i = threadIdx.x; i < COUT * CH; i += 256) {
            int co = i / CH, ch = i - co * CH;
            int src = (tap * COUT + co) * CIN + ch * 8;
            int dst = co * PITCH + ch * 8;
            *(bf16x8*)&wl[dst] = *(const bf16x8*)&w_hi[src];
            *(bf16x8*)&wl[COUT * PITCH + dst] = *(const bf16x8*)&w_lo[src];
        }
        __syncthreads();
#pragma unroll
        for (int kc = 0; kc < CIN / 32; ++kc) {
            bf16x8 ah[5], al[5];
#pragma unroll
            for (int mt = 0; mt < 5; ++mt) {
                const int off = abase[mt] + tapoff + kc * 32;
                ah[mt] = *(const bf16x8*)&in_hi[off];
                al[mt] = *(const bf16x8*)&in_lo[off];
            }
#pragma unroll
            for (int nt = 0; nt < NT; ++nt) {
                const int woff = (nt * 16 + m) * PITCH + kc * 32 + q * 8;
                bf16x8 bh = *(const bf16x8*)&wl[woff];
                bf16x8 bl = *(const bf16x8*)&wl[COUT * PITCH + woff];
#pragma unroll
                for (int mt = 0; mt < 5; ++mt) {
                    acc[mt][nt] = __builtin_amdgcn_mfma_f32_16x16x32_bf16(ah[mt], bh, acc[mt][nt], 0, 0, 0);
                    acc[mt][nt] = __builtin_amdgcn_mfma_f32_16x16x32_bf16(ah[mt], bl, acc[mt][nt], 0, 0, 0);
                    acc[mt][nt] = __builtin_amdgcn_mfma_f32_16x16x32_bf16(al[mt], bh, acc[mt][nt], 0, 0, 0);
                }
            }
        }
    }
    // epilogue: D col = lane&15 = co, D row = q*4+r = pixel within m-tile
#pragma unroll
    for (int nt = 0; nt < NT; ++nt) {
        const int co = nt * 16 + m;
        const float bv = bias[co];
#pragma unroll
        for (int mt = 0; mt < 5; ++mt) {
#pragma unroll
            for (int r = 0; r < 4; ++r) {
                float v = acc[mt][nt][r] + bv;
                v = (v > 0.f) ? v : 0.1f * v;
                const int x = x0 + mt * 16 + q * 4 + r;
                if (OUTF) {
                    out_f[((size_t)(b * COUT + co)) * HW + y * W + x] = v;
                } else {
                    const size_t off = ((size_t)(b * WP + y + 1) * WP + (x + 1)) * COUT + co;
                    unsigned short h = f2bf(v);
                    out_hi[off] = h;
                    out_lo[off] = f2bf(v - bf2f(h));
                }
            }
        }
    }
}

// ---------------- fused heads (5x5 convs) + warp + sigmoid ----------------
__global__ __launch_bounds__(256) void k_head(const float* __restrict__ x3,
                                              const float* __restrict__ wHT,
                                              const float* __restrict__ disp_b,
                                              const float* __restrict__ conf_b,
                                              const float* __restrict__ flow_up,
                                              float* __restrict__ out) {
    const int b = blockIdx.z;
    const int x0 = blockIdx.x * 16, y0 = blockIdx.y * 16;
    const int tx = threadIdx.x, ty = threadIdx.y;
    const int tid = ty * 16 + tx;
    __shared__ float sh[2 * 400];  // 2 channels x 20x20
    float a0 = 0.f, a1 = 0.f, a2 = 0.f;
    const float* xb = x3 + (size_t)(b * 32) * HW;
    for (int ci = 0; ci < 32; ci += 2) {
        __syncthreads();
        for (int i = tid; i < 800; i += 256) {
            int cc = i / 400;
            int rem = i - cc * 400;
            int r = rem / 20, c2 = rem % 20;
            int gy = y0 + r - 2, gx = x0 + c2 - 2;
            float v = 0.f;
            if (gy >= 0 && gy < H && gx >= 0 && gx < W)
                v = xb[(size_t)(ci + cc) * HW + gy * W + gx];
            sh[i] = v;
        }
        __syncthreads();
#pragma unroll
        for (int cc = 0; cc < 2; ++cc) {
            const float* t = sh + cc * 400;
            const float* wp = wHT + (size_t)(ci + cc) * 75;
#pragma unroll
            for (int k = 0; k < 25; ++k) {
                float v = t[(ty + k / 5) * 20 + tx + (k % 5)];
                a0 += v * wp[k * 3 + 0];
                a1 += v * wp[k * 3 + 1];
                a2 += v * wp[k * 3 + 2];
            }
        }
    }
    const int gx = x0 + tx, gy = y0 + ty;
    float d0 = a0 + disp_b[0];
    float d1 = a1 + disp_b[1];
    float cf = a2 + conf_b[0];
    cf = 1.f / (1.f + expf(-cf));

    float px = (float)gx + d0, py = (float)gy + d1;
    float x0f = floorf(px), y0f = floorf(py);
    float wx1 = px - x0f, wx0 = 1.f - wx1;
    float wy1 = py - y0f, wy0 = 1.f - wy1;
    const float* f0 = flow_up + (size_t)(b * 2) * HW;
    const float* f1 = f0 + HW;

    float m00, m01, m10, m11;
    float a00, a01, a10, a11;
    float b00, b01, b10, b11;
    auto corner = [&](float xf, float yf, float& m, float& c0, float& c1) {
        bool valid = (xf >= 0.f) && (xf <= (float)(W - 1)) && (yf >= 0.f) && (yf <= (float)(H - 1));
        m = valid ? 1.f : 0.f;
        if (valid) {
            int xi = (int)xf, yi = (int)yf;
            int o = yi * W + xi;
            c0 = f0[o]; c1 = f1[o];
        } else { c0 = 0.f; c1 = 0.f; }
    };
    corner(x0f,       y0f,       m00, a00, b00);
    corner(x0f + 1.f, y0f,       m01, a01, b01);
    corner(x0f,       y0f + 1.f, m10, a10, b10);
    corner(x0f + 1.f, y0f + 1.f, m11, a11, b11);

    float o0 = wy0 * (wx0 * a00 + wx1 * a01) + wy1 * (wx0 * a10 + wx1 * a11);
    float o1 = wy0 * (wx0 * b00 + wx1 * b01) + wy1 * (wx0 * b10 + wx1 * b11);
    float msk = wy0 * (wx0 * m00 + wx1 * m01) + wy1 * (wx0 * m10 + wx1 * m11);
    float mask = (msk >= 1.f) ? 1.f : 0.f;

    int o = gy * W + gx;
    out[(size_t)(b * 2 + 0) * HW + o] = o0 * mask;
    out[(size_t)(b * 2 + 1) * HW + o] = o1 * mask;
    out[(size_t)B * 2 * HW + (size_t)b * HW + o] = cf;
}

extern "C" void kernel_launch(void* const* d_in, const int* in_sizes, int n_in,
                              void* d_out, int out_size, void* d_ws, size_t ws_size,
                              hipStream_t stream) {
    const float* feats     = (const float*)d_in[0];
    const float* flow      = (const float*)d_in[1];
    const float* conf      = (const float*)d_in[2];
    const float* up_conf_w = (const float*)d_in[3];
    const float* up_flow_w = (const float*)d_in[4];
    const float* w1        = (const float*)d_in[5];
    const float* b1        = (const float*)d_in[6];
    const float* w2        = (const float*)d_in[7];
    const float* b2        = (const float*)d_in[8];
    const float* w3        = (const float*)d_in[9];
    const float* b3        = (const float*)d_in[10];
    const float* disp_w    = (const float*)d_in[11];
    const float* disp_b    = (const float*)d_in[12];
    const float* conf_w    = (const float*)d_in[13];
    const float* conf_b    = (const float*)d_in[14];
    float* out = (float*)d_out;

    // workspace layout (bytes)
    char* p = (char*)d_ws;
    const size_t SZ_XIN = (size_t)B * WP * WP * 64 * 2;    // 26,873,856 per buffer
    const size_t SZ_X1  = (size_t)B * WP * WP * 128 * 2;   // 53,747,712 per buffer
    unsigned short* xin_hi = (unsigned short*)p;                     // +0
    unsigned short* xin_lo = (unsigned short*)(p + SZ_XIN);          // +26.9M
    unsigned short* x1_hi  = (unsigned short*)(p + 2 * SZ_XIN);      // +53.7M
    unsigned short* x1_lo  = (unsigned short*)(p + 2 * SZ_XIN + SZ_X1);
    char* p2 = p + 2 * SZ_XIN + 2 * SZ_X1;                           // +161.2M
    float* flow_up = (float*)p2;                 // 1,638,400 B
    float* wHT     = (float*)(p2 + 1638400);     // 9,600 B
    unsigned short* wpk1h = (unsigned short*)(p2 + 1648000);
    unsigned short* wpk1l = wpk1h + 73728;
    unsigned short* wpk2h = wpk1l + 73728;
    unsigned short* wpk2l = wpk2h + 73728;
    unsigned short* wpk3h = wpk2l + 73728;
    unsigned short* wpk3l = wpk3h + 18432;
    // aliases: x2 reuses xin (same geometry C=64, ring stays zero); x3 reuses x1_hi
    unsigned short* x2_hi = xin_hi;
    unsigned short* x2_lo = xin_lo;
    float* x3 = (float*)(p + 2 * SZ_XIN);        // 26.2 MB <= SZ_X1, x1 dead after conv2

    k_repack<<<658, 256, 0, stream>>>(w1, w2, w3, disp_w, conf_w,
                                      wpk1h, wpk1l, wpk2h, wpk2l, wpk3h, wpk3l, wHT);
    k_zeropad<<<484, 256, 0, stream>>>(xin_hi, xin_lo, x1_hi, x1_lo);
    k_upsample<<<(B * 3 * HW + 255) / 256, 256, 0, stream>>>(flow, conf, up_flow_w, up_conf_w,
                                                             flow_up, xin_hi, xin_lo);
    k_corr<<<dim3(5, 20, B), dim3(32, 8), 0, stream>>>(feats, xin_hi, xin_lo);
    k_convM<64, 128, 0><<<dim3(80, 1, B), 256, 0, stream>>>(xin_hi, xin_lo, wpk1h, wpk1l, b1,
                                                            x1_hi, x1_lo, nullptr);
    k_convM<128, 64, 0><<<dim3(80, 1, B), 256, 0, stream>>>(x1_hi, x1_lo, wpk2h, wpk2l, b2,
                                                            x2_hi, x2_lo, nullptr);
    k_convM<64, 32, 1><<<dim3(80, 1, B), 256, 0, stream>>>(x2_hi, x2_lo, wpk3h, wpk3l, b3,
                                                           nullptr, nullptr, x3);
    k_head<<<dim3(10, 10, B), dim3(16, 16), 0, stream>>>(x3, wHT, disp_b, conf_b, flow_up, out);
}